// Round 2
// baseline (255.744 us; speedup 1.0000x reference)
//
#include <hip/hip_runtime.h>
#include <math.h>

// Problem constants (fixed by the reference setup_inputs).
constexpr int B = 8, N = 16384, P = 512, D = 64;
constexpr int CHUNK = 256;        // rows per block (of N)
constexpr int STAGE_ROWS = 128;   // rows per LDS stage

// ws layout (float offsets)
//   p_norm : [0,            P*D)          normalized prototypes
//   p2     : [P*D,          P*D+P)        ||p||^2 after normalize
//   x2     : [P*D+P,        P*D+P+B*N)    per-row ||x||^2
//   minkey : u64[B*P] after that (8B aligned)
constexpr size_t OFF_P  = 0;
constexpr size_t OFF_P2 = (size_t)P * D;
constexpr size_t OFF_X2 = OFF_P2 + P;
constexpr size_t OFF_MK_BYTES = (OFF_X2 + (size_t)B * N) * sizeof(float); // 657408, 8B-aligned

__global__ void kinit(unsigned long long* __restrict__ mk) {
    int i = blockIdx.x * 256 + threadIdx.x;
    if (i < B * P) mk[i] = ~0ull;
}

// One thread per prototype: L2-normalize, write normalized row + p2.
__global__ void knorm(const float* __restrict__ proto,
                      float* __restrict__ pn, float* __restrict__ p2) {
    int j = blockIdx.x * 64 + threadIdx.x;
    if (j >= P) return;
    const float4* pr = reinterpret_cast<const float4*>(proto + (size_t)j * D);
    float a0 = 0.f, a1 = 0.f, a2 = 0.f, a3 = 0.f;
    float4 v[16];
    #pragma unroll
    for (int i = 0; i < 16; ++i) {
        v[i] = pr[i];
        a0 = fmaf(v[i].x, v[i].x, a0);
        a1 = fmaf(v[i].y, v[i].y, a1);
        a2 = fmaf(v[i].z, v[i].z, a2);
        a3 = fmaf(v[i].w, v[i].w, a3);
    }
    float nrm = sqrtf((a0 + a1) + (a2 + a3));
    float sc = 1.0f / fmaxf(nrm, 1e-12f);
    float q0 = 0.f, q1 = 0.f, q2 = 0.f, q3 = 0.f;
    float4* dst = reinterpret_cast<float4*>(pn + (size_t)j * D);
    #pragma unroll
    for (int i = 0; i < 16; ++i) {
        float4 q;
        q.x = v[i].x * sc; q.y = v[i].y * sc; q.z = v[i].z * sc; q.w = v[i].w * sc;
        dst[i] = q;
        q0 = fmaf(q.x, q.x, q0);
        q1 = fmaf(q.y, q.y, q1);
        q2 = fmaf(q.z, q.z, q2);
        q3 = fmaf(q.w, q.w, q3);
    }
    p2[j] = (q0 + q1) + (q2 + q3);
}

// 16 lanes per row, float4 loads, shuffle-tree reduce -> x2 per row.
__global__ void kx2(const float* __restrict__ x, float* __restrict__ x2w) {
    int t = threadIdx.x;
    int row = blockIdx.x * 16 + (t >> 4);
    int l = t & 15;
    float4 v = reinterpret_cast<const float4*>(x + (size_t)row * D)[l];
    float s = (v.x * v.x + v.y * v.y) + (v.z * v.z + v.w * v.w);
    s += __shfl_xor(s, 1);
    s += __shfl_xor(s, 2);
    s += __shfl_xor(s, 4);
    s += __shfl_xor(s, 8);
    if (l == 0) x2w[row] = s;
}

// Main: thread t owns prototype t (64 f32 in VGPRs). x staged in LDS,
// read broadcast (uniform address across the wave -> conflict-free).
// Running (min sq, idx) per thread; one u64 atomicMin per thread per block.
__global__ __launch_bounds__(512, 4)
void kmain(const float* __restrict__ x, const float* __restrict__ pn,
           const float* __restrict__ p2w, const float* __restrict__ x2w,
           unsigned long long* __restrict__ mk) {
    __shared__ float4 xs[STAGE_ROWS][D / 4];
    __shared__ float x2s[STAGE_ROWS];

    const int t  = threadIdx.x;      // prototype index
    const int b  = blockIdx.y;
    const int n0 = blockIdx.x * CHUNK;

    float4 pr[16];
    const float4* psrc = reinterpret_cast<const float4*>(pn + (size_t)t * D);
    #pragma unroll
    for (int i = 0; i < 16; ++i) pr[i] = psrc[i];
    const float p2 = p2w[t];

    float best = 3.4e38f;
    int   bidx = 0;

    for (int s = 0; s < CHUNK / STAGE_ROWS; ++s) {
        const int nb = n0 + s * STAGE_ROWS;
        __syncthreads();
        const float4* src = reinterpret_cast<const float4*>(x + ((size_t)b * N + nb) * D);
        float4* xsf = &xs[0][0];
        #pragma unroll
        for (int i = 0; i < (STAGE_ROWS * (D / 4)) / 512; ++i)
            xsf[t + i * 512] = src[t + i * 512];
        if (t < STAGE_ROWS) x2s[t] = x2w[(size_t)b * N + nb + t];
        __syncthreads();

        for (int r = 0; r < STAGE_ROWS; ++r) {
            float a0 = 0.f, a1 = 0.f, a2 = 0.f, a3 = 0.f;
            #pragma unroll
            for (int d = 0; d < 16; ++d) {
                float4 xv = xs[r][d];
                a0 = fmaf(xv.x, pr[d].x, a0);
                a1 = fmaf(xv.y, pr[d].y, a1);
                a2 = fmaf(xv.z, pr[d].z, a2);
                a3 = fmaf(xv.w, pr[d].w, a3);
            }
            float dot = (a0 + a1) + (a2 + a3);
            float sq = fmaf(-2.0f, dot, x2s[r] + p2);
            sq = fmaxf(sq, 0.0f);
            if (sq < best) { best = sq; bidx = nb + r; }
        }
    }

    unsigned long long key =
        ((unsigned long long)__float_as_uint(best) << 32) | (unsigned)bidx;
    atomicMin(&mk[(size_t)b * P + t], key);
}

__global__ void kfin(const unsigned long long* __restrict__ mk,
                     float* __restrict__ out) {
    int i = blockIdx.x * 256 + threadIdx.x;
    if (i >= B * P) return;
    unsigned long long k = mk[i];
    float sq = __uint_as_float((unsigned)(k >> 32));
    out[i] = sqrtf(sq + 1e-8f);                              // prototype_dist
    out[B * P + i] = (float)(unsigned)(k & 0xFFFFFFFFu);     // patches_idcs (as f32)
}

extern "C" void kernel_launch(void* const* d_in, const int* in_sizes, int n_in,
                              void* d_out, int out_size, void* d_ws, size_t ws_size,
                              hipStream_t stream) {
    const float* x     = (const float*)d_in[0];
    const float* proto = (const float*)d_in[1];
    float* out = (float*)d_out;

    float* wsf = (float*)d_ws;
    float* pn  = wsf + OFF_P;
    float* p2  = wsf + OFF_P2;
    float* x2w = wsf + OFF_X2;
    unsigned long long* mk =
        (unsigned long long*)((char*)d_ws + OFF_MK_BYTES);

    kinit<<<dim3((B * P + 255) / 256), dim3(256), 0, stream>>>(mk);
    knorm<<<dim3(P / 64), dim3(64), 0, stream>>>(proto, pn, p2);
    kx2<<<dim3((B * N) / 16), dim3(256), 0, stream>>>(x, x2w);
    kmain<<<dim3(N / CHUNK, B), dim3(512), 0, stream>>>(x, pn, p2, x2w, mk);
    kfin<<<dim3((B * P + 255) / 256), dim3(256), 0, stream>>>(mk, out);
}

// Round 3
// 206.044 us; speedup vs baseline: 1.2412x; 1.2412x over previous
//
#include <hip/hip_runtime.h>
#include <math.h>

// Problem constants (fixed by the reference setup_inputs).
constexpr int B = 8, N = 16384, P = 512, D = 64;
constexpr int TM = 128;   // rows per block tile
constexpr int TP = 128;   // protos per block tile

using u64 = unsigned long long;

// ws layout: pn f32[P*D] | p2 f32[P] | mk u64[B*P]
constexpr size_t OFF_P2 = (size_t)P * D;                         // float offset
constexpr size_t OFF_MK = ((size_t)P * D + P) * sizeof(float);   // byte offset (133120, 8B-aligned)

// Fused: init min-keys + L2-normalize prototypes (+ p2).
__global__ void kprep(const float* __restrict__ proto, float* __restrict__ pn,
                      float* __restrict__ p2, u64* __restrict__ mk) {
    int gid = blockIdx.x * 256 + threadIdx.x;
    if (gid < B * P) mk[gid] = ~0ull;
    if (gid < P) {
        const float4* pr = reinterpret_cast<const float4*>(proto + (size_t)gid * D);
        float a0 = 0.f, a1 = 0.f, a2 = 0.f, a3 = 0.f;
        float4 v[16];
        #pragma unroll
        for (int i = 0; i < 16; ++i) {
            v[i] = pr[i];
            a0 = fmaf(v[i].x, v[i].x, a0);
            a1 = fmaf(v[i].y, v[i].y, a1);
            a2 = fmaf(v[i].z, v[i].z, a2);
            a3 = fmaf(v[i].w, v[i].w, a3);
        }
        float nrm = sqrtf((a0 + a1) + (a2 + a3));
        float sc = 1.0f / fmaxf(nrm, 1e-12f);
        float q0 = 0.f, q1 = 0.f, q2 = 0.f, q3 = 0.f;
        float4* dst = reinterpret_cast<float4*>(pn + (size_t)gid * D);
        #pragma unroll
        for (int i = 0; i < 16; ++i) {
            float4 q;
            q.x = v[i].x * sc; q.y = v[i].y * sc; q.z = v[i].z * sc; q.w = v[i].w * sc;
            dst[i] = q;
            q0 = fmaf(q.x, q.x, q0);
            q1 = fmaf(q.y, q.y, q1);
            q2 = fmaf(q.z, q.z, q2);
            q3 = fmaf(q.w, q.w, q3);
        }
        p2[gid] = (q0 + q1) + (q2 + q3);
    }
}

// Register-tiled main kernel: 256 threads, 128 rows x 128 protos per block,
// 8x8 f32 accumulator tile per thread, K=64 resident in LDS (k-major, XOR-swizzled).
__global__ __launch_bounds__(256, 2)
void kmain(const float* __restrict__ x, const float* __restrict__ pn,
           const float* __restrict__ p2w, u64* __restrict__ mk) {
    // smem: xs[64][128] (32KB) | ps[64][128] (32KB) | x2s[128] | p2s[128]
    __shared__ __align__(16) char smem[66560];
    float (*xs)[TM] = reinterpret_cast<float(*)[TM]>(smem);
    float (*ps)[TP] = reinterpret_cast<float(*)[TP]>(smem + 32768);
    float* x2s = reinterpret_cast<float*>(smem + 65536);
    float* p2s = reinterpret_cast<float*>(smem + 66048);

    const int t   = threadIdx.x;
    const int b   = blockIdx.z;
    const int n0  = blockIdx.x * TM;
    const int pt0 = blockIdx.y * TP;
    const int tx  = t & 15;     // proto group (stride-16 protos: p = j*16+tx)
    const int ty  = t >> 4;     // row group   (rows ty*8 .. ty*8+7)

    // ---- Stage x tile transposed (k-major) with XOR swizzle; fold in x2. ----
    // swizzle: column = row ^ s(k), s(k) = ((k>>2)&7)<<2  -> staging writes hit
    // all 32 banks (<=2-way, free); reads apply the same XOR.
    {
        const float4* xsrc = reinterpret_cast<const float4*>(x + ((size_t)b * N + n0) * D);
        #pragma unroll
        for (int i = 0; i < 8; ++i) {
            int f   = t + i * 256;        // float4 index in tile [0,2048)
            float4 v = xsrc[f];
            int row = f >> 4;             // local row
            int k4  = f & 15;             // float4 within row: k = k4*4+c
            int s   = (k4 & 7) << 2;      // ((k>>2)&7)<<2, same for c=0..3
            int col = row ^ s;
            xs[k4 * 4 + 0][col] = v.x;
            xs[k4 * 4 + 1][col] = v.y;
            xs[k4 * 4 + 2][col] = v.z;
            xs[k4 * 4 + 3][col] = v.w;
            float d4 = (v.x * v.x + v.y * v.y) + (v.z * v.z + v.w * v.w);
            d4 += __shfl_xor(d4, 1);
            d4 += __shfl_xor(d4, 2);
            d4 += __shfl_xor(d4, 4);
            d4 += __shfl_xor(d4, 8);
            if ((t & 15) == 0) x2s[row] = d4;   // 16 lanes of a row -> lane q==0
        }
        const float4* psrc = reinterpret_cast<const float4*>(pn + (size_t)pt0 * D);
        #pragma unroll
        for (int i = 0; i < 8; ++i) {
            int f   = t + i * 256;
            float4 v = psrc[f];
            int pp  = f >> 4;             // local proto
            int k4  = f & 15;
            int s   = (k4 & 7) << 2;
            int col = pp ^ s;
            ps[k4 * 4 + 0][col] = v.x;
            ps[k4 * 4 + 1][col] = v.y;
            ps[k4 * 4 + 2][col] = v.z;
            ps[k4 * 4 + 3][col] = v.w;
        }
        if (t < TP) p2s[t] = p2w[pt0 + t];
    }
    __syncthreads();

    // ---- Compute: acc[r][j] = dot(x[row ty*8+r], p[proto j*16+tx]) ----
    float acc[8][8] = {};
    #pragma unroll 4
    for (int k = 0; k < D; ++k) {
        int s = ((k >> 2) & 7) << 2;
        // x fragment: two conflict-free broadcast b128 reads
        float4 xa = *reinterpret_cast<const float4*>(&xs[k][(ty * 8) ^ s]);
        float4 xb = *reinterpret_cast<const float4*>(&xs[k][(ty * 8 + 4) ^ s]);
        float xv[8] = {xa.x, xa.y, xa.z, xa.w, xb.x, xb.y, xb.z, xb.w};
        // p fragment: stride-16 scalar reads -> 16 distinct banks, broadcast, free
        float pv[8];
        #pragma unroll
        for (int j = 0; j < 8; ++j) pv[j] = ps[k][(j * 16 + tx) ^ s];
        #pragma unroll
        for (int r = 0; r < 8; ++r)
            #pragma unroll
            for (int j = 0; j < 8; ++j)
                acc[r][j] = fmaf(xv[r], pv[j], acc[r][j]);
    }
    __syncthreads();   // done reading xs/ps; reuse xs as reduction buffer

    // ---- Epilogue: per-thread min over 8 rows, then cross-ty reduce in LDS ----
    u64* red = reinterpret_cast<u64*>(smem);   // [128 protos][17] u64 = 17408 B
    const int baseRow = n0 + ty * 8;
    #pragma unroll
    for (int j = 0; j < 8; ++j) {
        int pl = j * 16 + tx;
        float pp2 = p2s[pl];
        u64 bk = ~0ull;
        #pragma unroll
        for (int r = 0; r < 8; ++r) {
            float sq = fmaf(-2.0f, acc[r][j], x2s[ty * 8 + r] + pp2);
            sq = fmaxf(sq, 0.0f);
            u64 key = ((u64)__float_as_uint(sq) << 32) | (unsigned)(baseRow + r);
            bk = key < bk ? key : bk;   // equal sq -> lower idx wins (first occurrence)
        }
        red[pl * 17 + ty] = bk;
    }
    __syncthreads();
    if (t < TP) {
        u64 m = red[t * 17];
        #pragma unroll
        for (int q = 1; q < 16; ++q) {
            u64 c = red[t * 17 + q];
            m = c < m ? c : m;
        }
        atomicMin(&mk[(size_t)b * P + pt0 + t], m);
    }
}

__global__ void kfin(const u64* __restrict__ mk, float* __restrict__ out) {
    int i = blockIdx.x * 256 + threadIdx.x;
    if (i >= B * P) return;
    u64 k = mk[i];
    float sq = __uint_as_float((unsigned)(k >> 32));
    out[i] = sqrtf(sq + 1e-8f);                              // prototype_dist
    out[B * P + i] = (float)(unsigned)(k & 0xFFFFFFFFu);     // patches_idcs (as f32)
}

extern "C" void kernel_launch(void* const* d_in, const int* in_sizes, int n_in,
                              void* d_out, int out_size, void* d_ws, size_t ws_size,
                              hipStream_t stream) {
    const float* x     = (const float*)d_in[0];
    const float* proto = (const float*)d_in[1];
    float* out = (float*)d_out;

    float* wsf = (float*)d_ws;
    float* pn  = wsf;
    float* p2  = wsf + OFF_P2;
    u64*   mk  = (u64*)((char*)d_ws + OFF_MK);

    kprep<<<dim3((B * P + 255) / 256), dim3(256), 0, stream>>>(proto, pn, p2, mk);
    kmain<<<dim3(N / TM, P / TP, B), dim3(256), 0, stream>>>(x, pn, p2, mk);
    kfin<<<dim3((B * P + 255) / 256), dim3(256), 0, stream>>>(mk, out);
}

// Round 5
// 101.596 us; speedup vs baseline: 2.5173x; 2.0281x over previous
//
#include <hip/hip_runtime.h>
#include <math.h>

// Problem constants (fixed by the reference setup_inputs).
constexpr int B = 8, N = 16384, P = 512, D = 64;
constexpr int NSPLIT   = 16;              // N-splits (grid.x)
constexpr int ROWS_PB  = N / NSPLIT;      // 1024 rows per block
constexpr int CHUNK    = 128;             // rows per LDS chunk
constexpr int NCHUNK   = ROWS_PB / CHUNK; // 8
constexpr int TPB      = 256;             // protos per block (grid.y = P/TPB = 2)

typedef __attribute__((ext_vector_type(8))) _Float16 f16x8;  // 8 f16 = 4 VGPR
typedef __attribute__((ext_vector_type(4))) float f32x4;
typedef __attribute__((ext_vector_type(4))) int   i32x4;
using u32 = unsigned int;
using u64 = unsigned long long;

// LDS map (bytes):
//   xbuf0 : [0,     32768)   128 rows x 256B (2 f16 planes H|L, XOR-swizzled)
//   xbuf1 : [32768, 65536)
//   x2s   : [65536, 66560)   2 x 128 f32
//   p2s   : [69632, 70656)   256 f32
//   p-temp (phase P only): [0, 69632) = 256 rows x 272B stride (overlaps xbufs+x2s)
constexpr int X2S   = 65536;
constexpr int P2S   = 69632;
constexpr int SMEMB = 70656;

// f32 -> (f16 hi, f16 lo) exact-residual split; pack pairs of values.
__device__ __forceinline__ void cvt2(float a, float b, u32& hw, u32& lw) {
    _Float16 ha = (_Float16)a, hb = (_Float16)b;
    float ra = a - (float)ha, rb = b - (float)hb;     // exact
    _Float16 la = (_Float16)ra, lb = (_Float16)rb;
    hw = (u32)__builtin_bit_cast(unsigned short, ha) |
         ((u32)__builtin_bit_cast(unsigned short, hb) << 16);
    lw = (u32)__builtin_bit_cast(unsigned short, la) |
         ((u32)__builtin_bit_cast(unsigned short, lb) << 16);
}

__global__ __launch_bounds__(512, 2)
void kmain(const float* __restrict__ x, const float* __restrict__ proto,
           u64* __restrict__ pk) {
    __shared__ __align__(16) char smem[SMEMB];
    const int t  = threadIdx.x;
    const int l  = t & 63;
    const int wv = t >> 6;
    const int wr = wv >> 2, wc = wv & 3;     // wave 2x4 grid: 64 rows x 64 protos
    const int hi = l >> 4, il = l & 15;
    const int ns = blockIdx.x, pt = blockIdx.y, b = blockIdx.z;
    const int n0  = ns * ROWS_PB;
    const int pt0 = pt * TPB;

    // ---------- Phase P: normalize protos, split to 2 f16 planes in LDS ----------
    if (t < TPB) {
        const float4* pr4 = reinterpret_cast<const float4*>(proto + (size_t)(pt0 + t) * D);
        float a0 = 0.f, a1 = 0.f, a2 = 0.f, a3 = 0.f;
        float4 v[16];
        #pragma unroll
        for (int i = 0; i < 16; ++i) {
            v[i] = pr4[i];
            a0 = fmaf(v[i].x, v[i].x, a0);
            a1 = fmaf(v[i].y, v[i].y, a1);
            a2 = fmaf(v[i].z, v[i].z, a2);
            a3 = fmaf(v[i].w, v[i].w, a3);
        }
        float nrm = sqrtf((a0 + a1) + (a2 + a3));
        float sc  = 1.0f / fmaxf(nrm, 1e-12f);
        char* prow = smem + t * 272;   // p-temp row, stride 272B (4*row mod 32 bank spread)
        float q0 = 0.f, q1 = 0.f, q2 = 0.f, q3 = 0.f;
        #pragma unroll
        for (int g = 0; g < 8; ++g) {  // 8 k-values per group
            float4 va = v[2 * g], vb = v[2 * g + 1];
            float e[8] = {va.x * sc, va.y * sc, va.z * sc, va.w * sc,
                          vb.x * sc, vb.y * sc, vb.z * sc, vb.w * sc};
            q0 = fmaf(e[0], e[0], fmaf(e[4], e[4], q0));
            q1 = fmaf(e[1], e[1], fmaf(e[5], e[5], q1));
            q2 = fmaf(e[2], e[2], fmaf(e[6], e[6], q2));
            q3 = fmaf(e[3], e[3], fmaf(e[7], e[7], q3));
            u32 H[4], Lo[4];
            #pragma unroll
            for (int jj = 0; jj < 4; ++jj)
                cvt2(e[2 * jj], e[2 * jj + 1], H[jj], Lo[jj]);
            *reinterpret_cast<i32x4*>(prow +       g * 16) = i32x4{(int)H[0], (int)H[1], (int)H[2], (int)H[3]};
            *reinterpret_cast<i32x4*>(prow + 128 + g * 16) = i32x4{(int)Lo[0], (int)Lo[1], (int)Lo[2], (int)Lo[3]};
        }
        *reinterpret_cast<float*>(smem + P2S + t * 4) = (q0 + q1) + (q2 + q3);
    }
    __syncthreads();

    // ---------- Load B-fragments into registers ----------
    // mfma_f32_16x16x32_f16 B layout: lane l -> col = l&15, k = (l>>4)*8 + j
    f16x8 bh[2][4], bl[2][4];
    #pragma unroll
    for (int s = 0; s < 2; ++s)
        #pragma unroll
        for (int ni = 0; ni < 4; ++ni) {
            int row = wc * 64 + ni * 16 + il;       // local proto
            int off = s * 64 + hi * 16;             // kk = s*32 + hi*8
            bh[s][ni] = *reinterpret_cast<const f16x8*>(smem + row * 272 + off);
            bl[s][ni] = *reinterpret_cast<const f16x8*>(smem + row * 272 + 128 + off);
        }
    float p2c[4];
    #pragma unroll
    for (int ni = 0; ni < 4; ++ni)
        p2c[ni] = *reinterpret_cast<const float*>(smem + P2S + (wc * 64 + ni * 16 + il) * 4);
    __syncthreads();   // p-temp region now reusable as x buffers

    // per-lane A-frag address pieces (swizzle: off ^ ((row&7)<<4), row&7 == il&7;
    // bits 4-5 folded into alow, bit 6 applied to the s*64 term)
    const int alow  = (hi * 16) ^ ((il & 3) << 4);
    const int abit6 = (il & 4) << 4;
    int rowoff[4];
    #pragma unroll
    for (int mi = 0; mi < 4; ++mi)
        rowoff[mi] = (wr * 64 + mi * 16 + il) * 256 + alow;

    const float* gx = x + ((size_t)b * N + n0) * D + t * 16;  // row t>>2, quarter t&3

    // ---- staging: 16 f32 -> 2 f16 planes, swizzled ds_write; fold x2 ----
    auto stage = [&](const float4* L, int buf) {
        float vals[16] = {L[0].x, L[0].y, L[0].z, L[0].w, L[1].x, L[1].y, L[1].z, L[1].w,
                          L[2].x, L[2].y, L[2].z, L[2].w, L[3].x, L[3].y, L[3].z, L[3].w};
        float s16 = 0.f;
        #pragma unroll
        for (int i = 0; i < 16; ++i) s16 = fmaf(vals[i], vals[i], s16);
        s16 += __shfl_xor(s16, 1);
        s16 += __shfl_xor(s16, 2);
        int row = t >> 2, q = t & 3;
        if (q == 0) *reinterpret_cast<float*>(smem + X2S + buf * 512 + row * 4) = s16;
        char* base = smem + buf * 32768 + row * 256;
        int sw = (row & 7) << 4;
        #pragma unroll
        for (int hf = 0; hf < 2; ++hf) {
            u32 H[4], Lo[4];
            #pragma unroll
            for (int jj = 0; jj < 4; ++jj)
                cvt2(vals[hf * 8 + 2 * jj], vals[hf * 8 + 2 * jj + 1], H[jj], Lo[jj]);
            int ob = (q * 32 + hf * 16) ^ sw;
            *reinterpret_cast<i32x4*>(base +       ob) = i32x4{(int)H[0], (int)H[1], (int)H[2], (int)H[3]};
            *reinterpret_cast<i32x4*>(base + 128 + ob) = i32x4{(int)Lo[0], (int)Lo[1], (int)Lo[2], (int)Lo[3]};
        }
    };

    float4 L[4];
    #pragma unroll
    for (int i = 0; i < 4; ++i) L[i] = *reinterpret_cast<const float4*>(gx + i * 4);
    stage(L, 0);
    __syncthreads();

    float msq[4]  = {3.4e38f, 3.4e38f, 3.4e38f, 3.4e38f};
    int   midx[4] = {0, 0, 0, 0};

    for (int c = 0; c < NCHUNK; ++c) {
        const int buf = c & 1;
        if (c + 1 < NCHUNK) {
            const float* g2 = gx + (size_t)(c + 1) * CHUNK * D;
            #pragma unroll
            for (int i = 0; i < 4; ++i) L[i] = *reinterpret_cast<const float4*>(g2 + i * 4);
        }
        f32x4 acc[4][4];
        #pragma unroll
        for (int mi = 0; mi < 4; ++mi)
            #pragma unroll
            for (int ni = 0; ni < 4; ++ni) acc[mi][ni] = f32x4{0.f, 0.f, 0.f, 0.f};

        const int bufo = buf * 32768;
        #pragma unroll
        for (int s = 0; s < 2; ++s) {
            f16x8 ah[4], al[4];
            const int offh = (s * 64) ^ abit6;
            #pragma unroll
            for (int mi = 0; mi < 4; ++mi) {
                ah[mi] = *reinterpret_cast<const f16x8*>(smem + bufo + rowoff[mi] + offh);
                al[mi] = *reinterpret_cast<const f16x8*>(smem + bufo + rowoff[mi] + 128 + offh);
            }
            #pragma unroll
            for (int mi = 0; mi < 4; ++mi)
                #pragma unroll
                for (int ni = 0; ni < 4; ++ni) {
                    acc[mi][ni] = __builtin_amdgcn_mfma_f32_16x16x32_f16(
                        ah[mi], bh[s][ni], acc[mi][ni], 0, 0, 0);
                    acc[mi][ni] = __builtin_amdgcn_mfma_f32_16x16x32_f16(
                        ah[mi], bl[s][ni], acc[mi][ni], 0, 0, 0);
                    acc[mi][ni] = __builtin_amdgcn_mfma_f32_16x16x32_f16(
                        al[mi], bh[s][ni], acc[mi][ni], 0, 0, 0);
                }
        }

        // epilogue: sq = x2 + p2 - 2*dot; strict-< + ascending idx keeps first occurrence
        const float* x2p = reinterpret_cast<const float*>(smem + X2S + buf * 512);
        const int idxb = n0 + c * CHUNK + wr * 64 + hi * 4;
        #pragma unroll
        for (int mi = 0; mi < 4; ++mi) {
            f32x4 xv = *reinterpret_cast<const f32x4*>(x2p + wr * 64 + mi * 16 + hi * 4);
            #pragma unroll
            for (int ni = 0; ni < 4; ++ni) {
                #pragma unroll
                for (int r = 0; r < 4; ++r) {
                    float sq = fmaf(-2.0f, acc[mi][ni][r], xv[r] + p2c[ni]);
                    sq = fmaxf(sq, 0.0f);
                    int idx = idxb + mi * 16 + r;
                    if (sq < msq[ni]) { msq[ni] = sq; midx[ni] = idx; }
                }
            }
        }

        if (c + 1 < NCHUNK) stage(L, buf ^ 1);
        __syncthreads();
    }

    // ---------- reduce: u64 key = (sq_bits<<32)|idx; lower idx wins ties ----------
    u64 key[4];
    #pragma unroll
    for (int ni = 0; ni < 4; ++ni) {
        u64 k = ((u64)__float_as_uint(msq[ni]) << 32) | (u32)midx[ni];
        u64 o = __shfl_xor(k, 16); k = o < k ? o : k;
        o     = __shfl_xor(k, 32); k = o < k ? o : k;
        key[ni] = k;
    }
    u64 k01 = (l & 16) ? key[1] : key[0];
    u64 k23 = (l & 16) ? key[3] : key[2];
    u64 kk  = (l & 32) ? k23 : k01;          // proto_local = wc*64 + l
    u64* xch = reinterpret_cast<u64*>(smem);
    if (wr == 1) xch[wc * 64 + l] = kk;
    __syncthreads();
    if (wr == 0) {
        u64 o = xch[wc * 64 + l];
        kk = o < kk ? o : kk;
        pk[(size_t)ns * (B * P) + (size_t)b * P + pt0 + wc * 64 + l] = kk;
    }
}

__global__ void kfin(const u64* __restrict__ pk, float* __restrict__ out) {
    int i = blockIdx.x * 256 + threadIdx.x;
    if (i >= B * P) return;
    u64 m = pk[i];
    #pragma unroll
    for (int s = 1; s < NSPLIT; ++s) {
        u64 c = pk[(size_t)s * (B * P) + i];
        m = c < m ? c : m;
    }
    float sq = __uint_as_float((u32)(m >> 32));
    out[i] = sqrtf(sq + 1e-8f);                              // prototype_dist
    out[B * P + i] = (float)(u32)(m & 0xFFFFFFFFu);          // patches_idcs (as f32)
}

extern "C" void kernel_launch(void* const* d_in, const int* in_sizes, int n_in,
                              void* d_out, int out_size, void* d_ws, size_t ws_size,
                              hipStream_t stream) {
    const float* x     = (const float*)d_in[0];
    const float* proto = (const float*)d_in[1];
    float* out = (float*)d_out;
    u64* pk = (u64*)d_ws;   // NSPLIT * B * P * 8B = 512 KiB

    kmain<<<dim3(NSPLIT, P / TPB, B), dim3(512), 0, stream>>>(x, proto, pk);
    kfin<<<dim3((B * P + 255) / 256), dim3(256), 0, stream>>>(pk, out);
}